// Round 1
// baseline (69.047 us; speedup 1.0000x reference)
//
#include <hip/hip_runtime.h>
#include <math.h>

#define WIRES   4
#define LAYERS  3
#define PATCHES 196   // 14*14

// One block per batch element. First 196 threads each simulate one patch's
// 4-qubit circuit fully in registers (16 complex amplitudes). The 4 RZ gates
// of a layer are fused into one diagonal phase per basis state, precomputed
// per block into LDS (they depend only on q_params). Then a fused linear
// (784 -> 10) + log_softmax per block.
__global__ __launch_bounds__(256) void quanv_fused(
    const float* __restrict__ x,     // [B,1,28,28]
    const float* __restrict__ qp,    // [LAYERS,WIRES]
    const float* __restrict__ Wt,    // [10,784]
    const float* __restrict__ bias,  // [10]
    float* __restrict__ out)         // [B,10]
{
    __shared__ float feats[PATCHES * 4];      // 3136 B
    __shared__ float phr[LAYERS][16];         // fused RZ phase (real)
    __shared__ float phim[LAYERS][16];        // fused RZ phase (imag)
    __shared__ float wsum[4][10];
    __shared__ float lg[10];
    __shared__ float lse;

    const int b = blockIdx.x;
    const int t = threadIdx.x;

    // ---- precompute fused RZ phases: e^{i * sum_w (+-0.5*phi_w)} ----
    if (t < LAYERS * 16) {
        const int l = t >> 4, idx = t & 15;
        float th = 0.f;
        #pragma unroll
        for (int w = 0; w < 4; ++w) {
            // wire w lives at bit (3-w); bit==1 -> +phi/2, bit==0 -> -phi/2
            const float sgn = ((idx >> (3 - w)) & 1) ? 0.5f : -0.5f;
            th += sgn * qp[l * 4 + w];
        }
        float s, c;
        __sincosf(th, &s, &c);
        phr[l][idx]  = c;
        phim[l][idx] = s;
    }
    __syncthreads();

    // ---- per-patch circuit simulation ----
    if (t < PATCHES) {
        const int r = t / 14, cc = t % 14;
        const float* xb = x + b * 784;
        float ang[4];
        ang[0] = xb[(2 * r) * 28 + 2 * cc];        // tl -> wire 0
        ang[1] = xb[(2 * r) * 28 + 2 * cc + 1];    // tr -> wire 1
        ang[2] = xb[(2 * r + 1) * 28 + 2 * cc];    // bl -> wire 2
        ang[3] = xb[(2 * r + 1) * 28 + 2 * cc + 1];// br -> wire 3

        // RX angle is the same every layer: cos/sin once per wire
        float cw[4], sw[4];
        #pragma unroll
        for (int w = 0; w < 4; ++w) __sincosf(0.5f * ang[w], &sw[w], &cw[w]);

        // state: amp[i], i = w0*8 + w1*4 + w2*2 + w3
        float sr[16], si[16];
        #pragma unroll
        for (int i = 0; i < 16; ++i) { sr[i] = 0.f; si[i] = 0.f; }
        sr[0] = 1.f;

        #pragma unroll
        for (int l = 0; l < LAYERS; ++l) {
            // RX(ang[w]) on each wire: [[c, -i s],[-i s, c]]
            #pragma unroll
            for (int w = 0; w < 4; ++w) {
                const int m = 8 >> w;
                const float c = cw[w], s = sw[w];
                #pragma unroll
                for (int i = 0; i < 16; ++i) {
                    if (i & m) continue;
                    const int j = i | m;
                    const float a0r = sr[i], a0i = si[i];
                    const float a1r = sr[j], a1i = si[j];
                    sr[i] = fmaf(c, a0r,  s * a1i);
                    si[i] = fmaf(c, a0i, -s * a1r);
                    sr[j] = fmaf(c, a1r,  s * a0i);
                    si[j] = fmaf(c, a1i, -s * a0r);
                }
            }
            // CNOT(0,1): ctrl bit mask 8, tgt bit mask 4
            #pragma unroll
            for (int i = 0; i < 16; ++i) {
                if ((i & 8) && !(i & 4)) {
                    const int j = i ^ 4;
                    float tr = sr[i]; sr[i] = sr[j]; sr[j] = tr;
                    float ti = si[i]; si[i] = si[j]; si[j] = ti;
                }
            }
            // CNOT(2,3): ctrl bit mask 2, tgt bit mask 1
            #pragma unroll
            for (int i = 0; i < 16; ++i) {
                if ((i & 2) && !(i & 1)) {
                    const int j = i ^ 1;
                    float tr = sr[i]; sr[i] = sr[j]; sr[j] = tr;
                    float ti = si[i]; si[i] = si[j]; si[j] = ti;
                }
            }
            // fused RZ diagonal
            #pragma unroll
            for (int i = 0; i < 16; ++i) {
                const float pr = phr[l][i], pi = phim[l][i];
                const float rr = sr[i], ii = si[i];
                sr[i] = rr * pr - ii * pi;
                si[i] = rr * pi + ii * pr;
            }
        }

        // <Z_w> from probabilities
        float z[4] = {0.f, 0.f, 0.f, 0.f};
        #pragma unroll
        for (int i = 0; i < 16; ++i) {
            const float p = sr[i] * sr[i] + si[i] * si[i];
            #pragma unroll
            for (int w = 0; w < 4; ++w)
                z[w] += ((i >> (3 - w)) & 1) ? -p : p;
        }
        #pragma unroll
        for (int w = 0; w < 4; ++w) feats[t * 4 + w] = z[w];
    }
    __syncthreads();

    // ---- linear layer: logits[k] = feats . W[k,:] + bias[k] ----
    float part[10];
    #pragma unroll
    for (int k = 0; k < 10; ++k) part[k] = 0.f;
    for (int j = t; j < PATCHES * 4; j += 256) {
        const float f = feats[j];
        #pragma unroll
        for (int k = 0; k < 10; ++k) part[k] = fmaf(f, Wt[k * 784 + j], part[k]);
    }
    #pragma unroll
    for (int k = 0; k < 10; ++k) {
        #pragma unroll
        for (int off = 32; off > 0; off >>= 1)
            part[k] += __shfl_down(part[k], off, 64);
    }
    const int wave = t >> 6, lane = t & 63;
    if (lane == 0) {
        #pragma unroll
        for (int k = 0; k < 10; ++k) wsum[wave][k] = part[k];
    }
    __syncthreads();
    if (t < 10)
        lg[t] = bias[t] + wsum[0][t] + wsum[1][t] + wsum[2][t] + wsum[3][t];
    __syncthreads();
    if (t == 0) {
        float mx = lg[0];
        #pragma unroll
        for (int k = 1; k < 10; ++k) mx = fmaxf(mx, lg[k]);
        float se = 0.f;
        #pragma unroll
        for (int k = 0; k < 10; ++k) se += expf(lg[k] - mx);
        lse = mx + logf(se);
    }
    __syncthreads();
    if (t < 10) out[b * 10 + t] = lg[t] - lse;
}

extern "C" void kernel_launch(void* const* d_in, const int* in_sizes, int n_in,
                              void* d_out, int out_size, void* d_ws, size_t ws_size,
                              hipStream_t stream) {
    const float* x    = (const float*)d_in[0];
    const float* qp   = (const float*)d_in[1];
    const float* W    = (const float*)d_in[2];
    const float* bias = (const float*)d_in[3];
    float* out = (float*)d_out;

    const int B = in_sizes[0] / 784;  // 1024
    quanv_fused<<<B, 256, 0, stream>>>(x, qp, W, bias, out);
}

// Round 2
// 68.276 us; speedup vs baseline: 1.0113x; 1.0113x over previous
//
#include <hip/hip_runtime.h>
#include <math.h>

#define WIRES   4
#define LAYERS  3
#define PATCHES 196   // 14*14

// One block per batch element.
// Phase 0: coalesced float4 staging of the 784-float x row into LDS, while
//          threads 208..255 build the fused per-layer RZ phase tables.
// Phase 1: threads 0..195 each simulate one patch's 4-qubit circuit in
//          registers. Layer 1 is built analytically (|0000> -> product state:
//          24 real mults + quadrant folded into the RZ phase), layers 2..3 use
//          the RX butterfly. CNOTs are compile-time index permutations.
// Phase 2: fused 784->10 linear + log_softmax.
__global__ __launch_bounds__(256) void quanv_fused(
    const float* __restrict__ x,     // [B,1,28,28]
    const float* __restrict__ qp,    // [LAYERS,WIRES]
    const float* __restrict__ Wt,    // [10,784]
    const float* __restrict__ bias,  // [10]
    float* __restrict__ out)         // [B,10]
{
    __shared__ float xs[784];                 // staged x row
    __shared__ float feats[PATCHES * 4];
    __shared__ float phr[LAYERS][16];
    __shared__ float phim[LAYERS][16];
    __shared__ float wsum[4][10];
    __shared__ float lg[10];

    const int b = blockIdx.x;
    const int t = threadIdx.x;

    // ---- stage x row (coalesced float4) ----
    if (t < PATCHES) {
        reinterpret_cast<float4*>(xs)[t] =
            reinterpret_cast<const float4*>(x + (size_t)b * 784)[t];
    }
    // ---- fused RZ phases on otherwise-idle threads ----
    if (t >= 208 && t < 208 + LAYERS * 16) {
        const int idx16 = t - 208;
        const int l = idx16 >> 4, idx = idx16 & 15;
        float th = 0.f;
        #pragma unroll
        for (int w = 0; w < 4; ++w) {
            const float sgn = ((idx >> (3 - w)) & 1) ? 0.5f : -0.5f;
            th += sgn * qp[l * 4 + w];
        }
        float s, c;
        __sincosf(th, &s, &c);
        phr[l][idx]  = c;
        phim[l][idx] = s;
    }
    __syncthreads();

    // ---- per-patch circuit simulation ----
    if (t < PATCHES) {
        const int r = t / 14, cc = t % 14;
        float cw[4], sw[4];
        {
            const float a0 = xs[(2 * r) * 28 + 2 * cc];
            const float a1 = xs[(2 * r) * 28 + 2 * cc + 1];
            const float a2 = xs[(2 * r + 1) * 28 + 2 * cc];
            const float a3 = xs[(2 * r + 1) * 28 + 2 * cc + 1];
            __sincosf(0.5f * a0, &sw[0], &cw[0]);
            __sincosf(0.5f * a1, &sw[1], &cw[1]);
            __sincosf(0.5f * a2, &sw[2], &cw[2]);
            __sincosf(0.5f * a3, &sw[3], &cw[3]);
        }

        // ---- layer 1 analytically: amp_i = prod_w (bit ? -i*s_w : c_w) ----
        // magnitude products
        float m01[4], m23[4];
        m01[0] = cw[0] * cw[1]; m01[1] = cw[0] * sw[1];
        m01[2] = sw[0] * cw[1]; m01[3] = sw[0] * sw[1];
        m23[0] = cw[2] * cw[3]; m23[1] = cw[2] * sw[3];
        m23[2] = sw[2] * cw[3]; m23[3] = sw[2] * sw[3];

        float sr[16], si[16];
        // CNOT(0,1) then CNOT(2,3) permute indices; then RZ layer-0 phase,
        // with the (-i)^popcount quadrant folded in. All compile-time.
        #pragma unroll
        for (int i = 0; i < 16; ++i) {
            const float m = m01[i >> 2] * m23[i & 3];
            int ti = (i & 8) ? (i ^ 4) : i;
            ti = (ti & 2) ? (ti ^ 1) : ti;
            const int pc = ((i >> 3) & 1) + ((i >> 2) & 1) + ((i >> 1) & 1) + (i & 1);
            const float pr = phr[0][ti], pi = phim[0][ti];
            float rr, ii;
            switch (pc & 3) {      // amp * (-i)^pc, then * (pr + i*pi)
                case 0: rr =  m * pr; ii =  m * pi; break;  // ( m, 0)
                case 1: rr =  m * pi; ii = -m * pr; break;  // ( 0,-m)
                case 2: rr = -m * pr; ii = -m * pi; break;  // (-m, 0)
                default:rr = -m * pi; ii =  m * pr; break;  // ( 0, m)
            }
            sr[ti] = rr; si[ti] = ii;
        }

        // ---- layers 2..3: RX butterflies + CNOT perms + RZ diagonal ----
        #pragma unroll
        for (int l = 1; l < LAYERS; ++l) {
            #pragma unroll
            for (int w = 0; w < 4; ++w) {
                const int m = 8 >> w;
                const float c = cw[w], s = sw[w];
                #pragma unroll
                for (int i = 0; i < 16; ++i) {
                    if (i & m) continue;
                    const int j = i | m;
                    const float a0r = sr[i], a0i = si[i];
                    const float a1r = sr[j], a1i = si[j];
                    sr[i] = fmaf(c, a0r,  s * a1i);
                    si[i] = fmaf(c, a0i, -s * a1r);
                    sr[j] = fmaf(c, a1r,  s * a0i);
                    si[j] = fmaf(c, a1i, -s * a0r);
                }
            }
            #pragma unroll
            for (int i = 0; i < 16; ++i) {   // CNOT(0,1)
                if ((i & 8) && !(i & 4)) {
                    const int j = i ^ 4;
                    float tr = sr[i]; sr[i] = sr[j]; sr[j] = tr;
                    float ti2 = si[i]; si[i] = si[j]; si[j] = ti2;
                }
            }
            #pragma unroll
            for (int i = 0; i < 16; ++i) {   // CNOT(2,3)
                if ((i & 2) && !(i & 1)) {
                    const int j = i ^ 1;
                    float tr = sr[i]; sr[i] = sr[j]; sr[j] = tr;
                    float ti2 = si[i]; si[i] = si[j]; si[j] = ti2;
                }
            }
            #pragma unroll
            for (int i = 0; i < 16; ++i) {   // fused RZ diagonal
                const float pr = phr[l][i], pi = phim[l][i];
                const float rr = sr[i], ii = si[i];
                sr[i] = rr * pr - ii * pi;
                si[i] = rr * pi + ii * pr;
            }
        }

        // ---- <Z_w> ----
        float z[4] = {0.f, 0.f, 0.f, 0.f};
        #pragma unroll
        for (int i = 0; i < 16; ++i) {
            const float p = fmaf(sr[i], sr[i], si[i] * si[i]);
            #pragma unroll
            for (int w = 0; w < 4; ++w)
                z[w] += ((i >> (3 - w)) & 1) ? -p : p;
        }
        #pragma unroll
        for (int w = 0; w < 4; ++w) feats[t * 4 + w] = z[w];
    }
    __syncthreads();

    // ---- linear layer ----
    float part[10];
    #pragma unroll
    for (int k = 0; k < 10; ++k) part[k] = 0.f;
    for (int j = t; j < PATCHES * 4; j += 256) {
        const float f = feats[j];
        #pragma unroll
        for (int k = 0; k < 10; ++k) part[k] = fmaf(f, Wt[k * 784 + j], part[k]);
    }
    #pragma unroll
    for (int k = 0; k < 10; ++k) {
        #pragma unroll
        for (int off = 32; off > 0; off >>= 1)
            part[k] += __shfl_down(part[k], off, 64);
    }
    const int wave = t >> 6, lane = t & 63;
    if (lane == 0) {
        #pragma unroll
        for (int k = 0; k < 10; ++k) wsum[wave][k] = part[k];
    }
    __syncthreads();
    if (t < 10)
        lg[t] = bias[t] + wsum[0][t] + wsum[1][t] + wsum[2][t] + wsum[3][t];
    __syncthreads();
    if (t < 10) {
        float mx = lg[0];
        #pragma unroll
        for (int k = 1; k < 10; ++k) mx = fmaxf(mx, lg[k]);
        float se = 0.f;
        #pragma unroll
        for (int k = 0; k < 10; ++k) se += expf(lg[k] - mx);
        out[b * 10 + t] = lg[t] - (mx + logf(se));
    }
}

extern "C" void kernel_launch(void* const* d_in, const int* in_sizes, int n_in,
                              void* d_out, int out_size, void* d_ws, size_t ws_size,
                              hipStream_t stream) {
    const float* x    = (const float*)d_in[0];
    const float* qp   = (const float*)d_in[1];
    const float* W    = (const float*)d_in[2];
    const float* bias = (const float*)d_in[3];
    float* out = (float*)d_out;

    const int B = in_sizes[0] / 784;  // 1024
    quanv_fused<<<B, 256, 0, stream>>>(x, qp, W, bias, out);
}

// Round 3
// 67.850 us; speedup vs baseline: 1.0176x; 1.0063x over previous
//
#include <hip/hip_runtime.h>
#include <math.h>

#define WIRES   4
#define LAYERS  3
#define PATCHES 196   // 14*14

// One block per batch element, 256 threads.
// - threads 0..195: each simulates one patch's 4-qubit circuit in registers.
//   Patch pixels loaded directly as two float2 (contiguous, 8B-aligned) -> no
//   LDS staging, no staging barrier.
// - threads 208..255 concurrently build the fused per-layer RZ phase tables.
// - Linear layer without LDS: thread t's z[4] pairs exactly with W[k][4t..4t+3]
//   (one float4 per class), then wave-shuffle + LDS cross-wave reduction.
__global__ __launch_bounds__(256) void quanv_fused(
    const float* __restrict__ x,     // [B,1,28,28]
    const float* __restrict__ qp,    // [LAYERS,WIRES]
    const float* __restrict__ Wt,    // [10,784]
    const float* __restrict__ bias,  // [10]
    float* __restrict__ out)         // [B,10]
{
    __shared__ float phr[LAYERS][16];
    __shared__ float phim[LAYERS][16];
    __shared__ float wsum[4][10];
    __shared__ float lg[10];

    const int b = blockIdx.x;
    const int t = threadIdx.x;

    // ---- direct patch loads + RX sincos (once; same angles every layer) ----
    float cw[4], sw[4];
    if (t < PATCHES) {
        const int r = t / 14, cc = t % 14;
        const float* xb = x + (size_t)b * 784;
        const float2 top = *reinterpret_cast<const float2*>(xb + (2 * r) * 28 + 2 * cc);
        const float2 bot = *reinterpret_cast<const float2*>(xb + (2 * r + 1) * 28 + 2 * cc);
        __sincosf(0.5f * top.x, &sw[0], &cw[0]);   // tl -> wire 0
        __sincosf(0.5f * top.y, &sw[1], &cw[1]);   // tr -> wire 1
        __sincosf(0.5f * bot.x, &sw[2], &cw[2]);   // bl -> wire 2
        __sincosf(0.5f * bot.y, &sw[3], &cw[3]);   // br -> wire 3
    }
    // ---- fused RZ phases on otherwise-idle threads ----
    if (t >= 208 && t < 208 + LAYERS * 16) {
        const int idx16 = t - 208;
        const int l = idx16 >> 4, idx = idx16 & 15;
        float th = 0.f;
        #pragma unroll
        for (int w = 0; w < 4; ++w) {
            const float sgn = ((idx >> (3 - w)) & 1) ? 0.5f : -0.5f;
            th += sgn * qp[l * 4 + w];
        }
        float s, c;
        __sincosf(th, &s, &c);
        phr[l][idx]  = c;
        phim[l][idx] = s;
    }
    __syncthreads();

    // ---- per-patch circuit simulation ----
    float z[4] = {0.f, 0.f, 0.f, 0.f};
    if (t < PATCHES) {
        // layer 1 analytically: amp_i = prod_w (bit ? -i*s_w : c_w)
        float m01[4], m23[4];
        m01[0] = cw[0] * cw[1]; m01[1] = cw[0] * sw[1];
        m01[2] = sw[0] * cw[1]; m01[3] = sw[0] * sw[1];
        m23[0] = cw[2] * cw[3]; m23[1] = cw[2] * sw[3];
        m23[2] = sw[2] * cw[3]; m23[3] = sw[2] * sw[3];

        float sr[16], si[16];
        // CNOT(0,1) then CNOT(2,3) permute indices; RZ layer-0 phase with the
        // (-i)^popcount quadrant folded in. All index math compile-time.
        #pragma unroll
        for (int i = 0; i < 16; ++i) {
            const float m = m01[i >> 2] * m23[i & 3];
            int ti = (i & 8) ? (i ^ 4) : i;
            ti = (ti & 2) ? (ti ^ 1) : ti;
            const int pc = ((i >> 3) & 1) + ((i >> 2) & 1) + ((i >> 1) & 1) + (i & 1);
            const float pr = phr[0][ti], pi = phim[0][ti];
            float rr, ii;
            switch (pc & 3) {      // amp * (-i)^pc, then * (pr + i*pi)
                case 0: rr =  m * pr; ii =  m * pi; break;
                case 1: rr =  m * pi; ii = -m * pr; break;
                case 2: rr = -m * pr; ii = -m * pi; break;
                default:rr = -m * pi; ii =  m * pr; break;
            }
            sr[ti] = rr; si[ti] = ii;
        }

        // layers 2..3: RX butterflies + CNOT perms + fused RZ diagonal
        #pragma unroll
        for (int l = 1; l < LAYERS; ++l) {
            #pragma unroll
            for (int w = 0; w < 4; ++w) {
                const int m = 8 >> w;
                const float c = cw[w], s = sw[w];
                #pragma unroll
                for (int i = 0; i < 16; ++i) {
                    if (i & m) continue;
                    const int j = i | m;
                    const float a0r = sr[i], a0i = si[i];
                    const float a1r = sr[j], a1i = si[j];
                    sr[i] = fmaf(c, a0r,  s * a1i);
                    si[i] = fmaf(c, a0i, -s * a1r);
                    sr[j] = fmaf(c, a1r,  s * a0i);
                    si[j] = fmaf(c, a1i, -s * a0r);
                }
            }
            #pragma unroll
            for (int i = 0; i < 16; ++i) {   // CNOT(0,1)
                if ((i & 8) && !(i & 4)) {
                    const int j = i ^ 4;
                    float tr = sr[i]; sr[i] = sr[j]; sr[j] = tr;
                    float ti2 = si[i]; si[i] = si[j]; si[j] = ti2;
                }
            }
            #pragma unroll
            for (int i = 0; i < 16; ++i) {   // CNOT(2,3)
                if ((i & 2) && !(i & 1)) {
                    const int j = i ^ 1;
                    float tr = sr[i]; sr[i] = sr[j]; sr[j] = tr;
                    float ti2 = si[i]; si[i] = si[j]; si[j] = ti2;
                }
            }
            #pragma unroll
            for (int i = 0; i < 16; ++i) {   // fused RZ diagonal
                const float pr = phr[l][i], pi = phim[l][i];
                const float rr = sr[i], ii = si[i];
                sr[i] = rr * pr - ii * pi;
                si[i] = rr * pi + ii * pr;
            }
        }

        // <Z_w> from probabilities
        #pragma unroll
        for (int i = 0; i < 16; ++i) {
            const float p = fmaf(sr[i], sr[i], si[i] * si[i]);
            #pragma unroll
            for (int w = 0; w < 4; ++w)
                z[w] += ((i >> (3 - w)) & 1) ? -p : p;
        }
    }

    // ---- linear layer, no LDS: thread t owns feature cols 4t..4t+3 ----
    float part[10];
    if (t < PATCHES) {
        const float4* W4 = reinterpret_cast<const float4*>(Wt);  // [10][196]
        #pragma unroll
        for (int k = 0; k < 10; ++k) {
            const float4 w = W4[k * 196 + t];
            part[k] = fmaf(z[0], w.x, fmaf(z[1], w.y, fmaf(z[2], w.z, z[3] * w.w)));
        }
    } else {
        #pragma unroll
        for (int k = 0; k < 10; ++k) part[k] = 0.f;
    }
    #pragma unroll
    for (int k = 0; k < 10; ++k) {
        #pragma unroll
        for (int off = 32; off > 0; off >>= 1)
            part[k] += __shfl_down(part[k], off, 64);
    }
    const int wave = t >> 6, lane = t & 63;
    if (lane == 0) {
        #pragma unroll
        for (int k = 0; k < 10; ++k) wsum[wave][k] = part[k];
    }
    __syncthreads();
    if (t < 10)
        lg[t] = bias[t] + wsum[0][t] + wsum[1][t] + wsum[2][t] + wsum[3][t];
    __syncthreads();
    if (t < 10) {
        float mx = lg[0];
        #pragma unroll
        for (int k = 1; k < 10; ++k) mx = fmaxf(mx, lg[k]);
        float se = 0.f;
        #pragma unroll
        for (int k = 0; k < 10; ++k) se += expf(lg[k] - mx);
        out[b * 10 + t] = lg[t] - (mx + logf(se));
    }
}

extern "C" void kernel_launch(void* const* d_in, const int* in_sizes, int n_in,
                              void* d_out, int out_size, void* d_ws, size_t ws_size,
                              hipStream_t stream) {
    const float* x    = (const float*)d_in[0];
    const float* qp   = (const float*)d_in[1];
    const float* W    = (const float*)d_in[2];
    const float* bias = (const float*)d_in[3];
    float* out = (float*)d_out;

    const int B = in_sizes[0] / 784;  // 1024
    quanv_fused<<<B, 256, 0, stream>>>(x, qp, W, bias, out);
}